// Round 2
// baseline (73.697 us; speedup 1.0000x reference)
//
#include <hip/hip_runtime.h>

#define S_DIM 363      // GRID = ceil(sqrt(2)*256)
#define S_P   368      // per-angle row stride in 8-B entries (16-B multiple)
#define A_DIM 180      // N_THETA
#define OUT_W 256
#define F_PI 3.14159265358979323846f

typedef float    f4 __attribute__((ext_vector_type(4)));
typedef _Float16 h4 __attribute__((ext_vector_type(4)));
union HU { uint2 u; h4 h; };

// Filtered sinogram, plain fp16 layout: g_sino[a*S_P + 1 + t] = y_a[t] for all
// 4 batches (8 B, batch-interleaved). Guards g[a][0] = g[a][364] = 0 reproduce
// the reference's clip+zero-weight edge semantics exactly (k1 = floor(pos)+1
// in [0,363]; lo = entry k1 = y[k1-1] or guard, hi = entry k1+1 = y[k1] or
// guard). Fully rewritten every call before kernel 2 reads it.
__device__ uint2 g_sino[A_DIM * S_P];

// ---------------------------------------------------------------------------
// Kernel 1: ramp filter as direct spatial convolution (exact rewrite of the
// reference FFT path: circular conv, g[0]=0.5, g[d]=-2/(pi*d)^2 for odd d,
// 0 for even d; |t-s| <= 362 < 512 so weight depends only on |t-s|).
// One block per angle, 192 threads (3 waves), TWO outputs per thread:
// t1 = tid, t2 = tid + 192 (same parity -> same opposite-parity s set), so
// each xs4[s] b128 read is shared by two outputs: LDS instrs per output drop
// 2 -> 1.5 (1 b128 + 2 b32 per s-iter for 2 outputs). Per-CU LDS issue
// 2184 -> 1638 wave-instrs. wt[] padded to 192 so t2-lanes past the edge read
// valid-but-discarded weights (no predication in the hot loop).
// ---------------------------------------------------------------------------
__global__ __launch_bounds__(192) void iradon_filter_kernel(
        const float* __restrict__ x) {
    __shared__ f4    xs4[S_DIM];   // per-s, batch-interleaved f32
    __shared__ float wt[192];      // wt[k] = -2/(pi*(2k+1))^2, padded to 192

    const int a   = blockIdx.x;    // 0..179
    const int tid = threadIdx.x;   // 0..191

    {   // stage s = tid and s = tid + 192 (covers 0..362)
        f4 v;
        v.x = x[(0 * S_DIM + tid) * A_DIM + a];
        v.y = x[(1 * S_DIM + tid) * A_DIM + a];
        v.z = x[(2 * S_DIM + tid) * A_DIM + a];
        v.w = x[(3 * S_DIM + tid) * A_DIM + a];
        xs4[tid] = v;
        const int s2 = tid + 192;
        if (s2 < S_DIM) {
            f4 w;
            w.x = x[(0 * S_DIM + s2) * A_DIM + a];
            w.y = x[(1 * S_DIM + s2) * A_DIM + a];
            w.z = x[(2 * S_DIM + s2) * A_DIM + a];
            w.w = x[(3 * S_DIM + s2) * A_DIM + a];
            xs4[s2] = w;
        }
    }
    {
        float d = (float)(2 * tid + 1);
        wt[tid] = -2.0f / (F_PI * F_PI * d * d);
    }
    __syncthreads();

    const int t1 = tid;
    const int t2 = tid + 192;                    // valid iff t2 < S_DIM
    f4 acc1 = 0.5f * xs4[t1];                    // d == 0 terms (f32 exact)
    f4 acc2 = 0.5f * xs4[(t2 < S_DIM) ? t2 : 0]; // clamped read; discarded if invalid

    const int s0 = 1 - (tid & 1);                // opposite parity of t1 (== t2 parity)
    #pragma unroll 4
    for (int s = s0; s < S_DIM; s += 2) {
        f4 v = xs4[s];                           // one b128, shared by both outputs
        int d1 = s - t1; d1 = (d1 < 0) ? -d1 : d1;
        int d2 = s - t2; d2 = (d2 < 0) ? -d2 : d2;   // <= 383 -> wt idx <= 191
        acc1 += wt[d1 >> 1] * v;                 // 2x v_pk_fma_f32 each
        acc2 += wt[d2 >> 1] * v;
    }

    HU r1; r1.h = __builtin_convertvector(acc1, h4);
    g_sino[a * S_P + 1 + t1] = r1.u;
    if (t2 < S_DIM) {
        HU r2; r2.h = __builtin_convertvector(acc2, h4);
        g_sino[a * S_P + 1 + t2] = r2.u;
    }
    if (tid == 190) { HU z; z.u.x = 0u; z.u.y = 0u; g_sino[a * S_P + 0]   = z.u; }
    if (tid == 191) { HU z; z.u.x = 0u; z.u.y = 0u; g_sino[a * S_P + 364] = z.u; }
}

// ---------------------------------------------------------------------------
// Kernel 2: backprojection. pos = (j-128)*cos - (i-128)*sin + 181.
// f = floor(pos), k1 = (int)f + 1 in [0,363]: lo = g[a][k1], hi = g[a][k1+1]
// -- two adjacent 8-B loads, second folds to offset:8. f32 accumulation via
// (float)half * f32 FMAs (v_fma_mix_f32). cos/sin now packed as float2 so the
// per-iter angle fetch is ONE ds_read_b64 (was two b32). Angle loop unrolled
// x5 for deeper VMEM pipelining (45 = 9*5).
// Block = 256 thr = 64(j) x 4 angle-quarters. Grid = 4 x 256.
// ---------------------------------------------------------------------------
__global__ __launch_bounds__(256) void iradon_backproject_kernel(
        float* __restrict__ out) {
    __shared__ float2 csn[A_DIM];
    __shared__ f4 red[256];

    const int tid = threadIdx.x;
    if (tid < A_DIM) {
        float th = (float)tid * (F_PI / 180.0f);
        csn[tid] = make_float2(cosf(th), sinf(th));
    }
    __syncthreads();

    const int px = tid & 63;
    const int q  = tid >> 6;           // wave index = angle quarter (uniform/wave)
    const int j  = blockIdx.x * 64 + px;
    const int i  = blockIdx.y;

    const float jj  = (float)(j - 128);
    const float nii = (float)(128 - i);    // -(i-128), wave-uniform

    f4 acc = (f4)0.0f;
    const int a0 = q * 45;
    #pragma unroll 5
    for (int m = 0; m < 45; ++m) {
        const int a = a0 + m;
        const float2 cn = csn[a];          // one ds_read_b64 broadcast
        float pos = fmaf(jj, cn.x, fmaf(nii, cn.y, 181.0f));
        float f   = floorf(pos);
        int   k1  = (int)f + 1;            // in [0, 363]
        float w1  = pos - f;
        float w0  = 1.0f - w1;
        const uint2* __restrict__ row = g_sino + a * S_P;
        HU lo, hi;
        lo.u = row[k1];                    // y[k]   x4 batches (8 B)
        hi.u = row[k1 + 1];                // y[k+1] x4 batches (offset:8)
        acc.x = fmaf((float)lo.h.x, w0, fmaf((float)hi.h.x, w1, acc.x));
        acc.y = fmaf((float)lo.h.y, w0, fmaf((float)hi.h.y, w1, acc.y));
        acc.z = fmaf((float)lo.h.z, w0, fmaf((float)hi.h.z, w1, acc.z));
        acc.w = fmaf((float)lo.h.w, w0, fmaf((float)hi.h.w, w1, acc.w));
    }

    red[tid] = acc;
    __syncthreads();

    if (tid < 64) {
        f4 r = red[tid] + red[tid + 64] + red[tid + 128] + red[tid + 192];
        r *= (F_PI / 360.0f);
        const int jo   = blockIdx.x * 64 + tid;
        const size_t p = (size_t)blockIdx.y * OUT_W + jo;
        out[p]              = r.x;
        out[p +     65536]  = r.y;
        out[p + 2 * 65536]  = r.z;
        out[p + 3 * 65536]  = r.w;
    }
}

extern "C" void kernel_launch(void* const* d_in, const int* in_sizes, int n_in,
                              void* d_out, int out_size, void* d_ws, size_t ws_size,
                              hipStream_t stream) {
    const float* x = (const float*)d_in[0];
    float* out = (float*)d_out;

    iradon_filter_kernel<<<dim3(A_DIM), 192, 0, stream>>>(x);
    iradon_backproject_kernel<<<dim3(4, OUT_W), 256, 0, stream>>>(out);
}